// Round 19
// baseline (71.385 us; speedup 1.0000x reference)
//
#include <hip/hip_runtime.h>

// Problem: B=8, CTX=1024, D=512 RoPE attention head, fp32 in/out, bf16-tolerance.
#define BATCH 8
#define CTXN  1024
#define DMODEL 512

using short8  = __attribute__((ext_vector_type(8))) short;
using f32x16  = __attribute__((ext_vector_type(16))) float;

typedef const void __attribute__((address_space(1)))* as1_cvp;
typedef void __attribute__((address_space(3)))* as3_vp;

__device__ __forceinline__ unsigned short f2bf(float f) {
  unsigned int u = __float_as_uint(f);
  u += 0x7fffu + ((u >> 16) & 1u);   // round-to-nearest-even
  return (unsigned short)(u >> 16);
}
__device__ __forceinline__ float bf2f(unsigned short u) {
  return __uint_as_float((unsigned int)u << 16);
}

// ---------------- prep: weight bf16 casts + RoPE cos/sin table (x cast ELIMINATED) -------
#define W4  65536     // 512*512/4
#define WCAST_BLOCKS 768   // 3*W4/256
__global__ __launch_bounds__(256) void prep_all(const float* __restrict__ wq,
                                                const float* __restrict__ wk,
                                                const float* __restrict__ wv,
                                                unsigned short* __restrict__ wb,
                                                float2* __restrict__ tab) {
  if (blockIdx.x < WCAST_BLOCKS) {
    int gid = blockIdx.x * 256 + threadIdx.x;
    const float4* src; ushort4* dst;
    if (gid < W4)            { src = (const float4*)wq + gid;            dst = (ushort4*)wb + gid; }
    else if (gid < 2 * W4)   { int o = gid - W4;     src = (const float4*)wk + o; dst = (ushort4*)(wb + 262144) + o; }
    else                     { int o = gid - 2 * W4; src = (const float4*)wv + o; dst = (ushort4*)(wb + 524288) + o; }
    float4 f = *src;
    ushort4 u;
    u.x = f2bf(f.x); u.y = f2bf(f.y); u.z = f2bf(f.z); u.w = f2bf(f.w);
    *dst = u;
  } else {
    int c = blockIdx.x - WCAST_BLOCKS;  // 0..1023
    int i = threadIdx.x;                // 0..255 = D/2
    float freq = exp2f((float)i * (-13.287712379549449f / 256.0f));  // 10000^(-i/256)
    float th = (float)c * freq;
    float sn, cs;
    sincosf(th, &sn, &cs);
    tab[c * 256 + i] = make_float2(cs, sn);
  }
}

// ---------------- qkv GEMM core 128x128 (8 waves), A staged from FP32 x ----------------
// A: reg-staged (4x global_load_dwordx4 -> cvt -> ds_write_b128, same XOR-swizzled bf16
// layout). B: global_load_lds as before. Bundle = 6 vmem ops; counted vmcnt(6) keeps one
// bundle in flight. A(t+1) cvt+write happens during iter t, slot readers drained at the
// mid-barrier of iter t-1; new lgkmcnt(0) before end barrier drains the ds_writes.
__device__ __forceinline__ void loadA_f32(const float* __restrict__ g, float4 aR[4], int tid) {
#pragma unroll
  for (int c = 0; c < 2; ++c) {
    int li  = (c << 9) + tid;            // bf16 16B-chunk index 0..1023
    int row = li >> 3;
    int chs = (li & 7) ^ (row & 7);      // pre-swizzled source chunk
    const float4* p = (const float4*)(g + (size_t)row * 512 + (chs << 3));
    aR[c * 2 + 0] = p[0];
    aR[c * 2 + 1] = p[1];
  }
}
__device__ __forceinline__ void writeA(unsigned short* sA, int slot, const float4 aR[4], int tid) {
#pragma unroll
  for (int c = 0; c < 2; ++c) {
    int li = (c << 9) + tid;
    const float4 f0 = aR[c * 2 + 0], f1 = aR[c * 2 + 1];
    short8 v;
    v[0] = (short)f2bf(f0.x); v[1] = (short)f2bf(f0.y);
    v[2] = (short)f2bf(f0.z); v[3] = (short)f2bf(f0.w);
    v[4] = (short)f2bf(f1.x); v[5] = (short)f2bf(f1.y);
    v[6] = (short)f2bf(f1.z); v[7] = (short)f2bf(f1.w);
    *(short8*)(sA + (slot << 13) + (li << 3)) = v;   // linear dest, matches aoff swizzle
  }
}
__device__ __forceinline__ void issueB(const unsigned short* __restrict__ gB, int ldB,
                                       unsigned short* sB, int slot, int tid) {
  unsigned short* dB = sB + (slot << 13);
#pragma unroll
  for (int c = 0; c < 2; ++c) {
    int li  = (c << 9) + tid;
    int row = li >> 3;
    int ch  = (li & 7) ^ (row & 7);
    __builtin_amdgcn_global_load_lds((as1_cvp)(gB + (size_t)row * ldB + (ch << 3)),
                                     (as3_vp)(dB + (li << 3)), 16, 0, 0);
  }
}

__device__ __forceinline__ void gemm_pipe_xf32(const float* __restrict__ gA,
                                               const unsigned short* __restrict__ gB, int ldB,
                                               unsigned short* sA, unsigned short* sB,
                                               int tid, f32x16 acc[2]) {
  const int l = tid & 63, w = tid >> 6, wr = w >> 2, wc = w & 3;
  const int cl = l & 31, hi = l >> 5;
  int aoff[2][4], boff[4];
#pragma unroll
  for (int m = 0; m < 2; ++m) {
    int ra = wr * 64 + m * 32 + cl;
#pragma unroll
    for (int ks = 0; ks < 4; ++ks) {
      int kc = ks * 2 + hi;
      aoff[m][ks] = ra * 64 + ((kc ^ (ra & 7)) << 3);
    }
  }
  {
    int rb = wc * 32 + cl;
#pragma unroll
    for (int ks = 0; ks < 4; ++ks) {
      int kc = ks * 2 + hi;
      boff[ks] = rb * 64 + ((kc ^ (rb & 7)) << 3);
    }
  }
  float4 aR0[4], aR1[4];
  // prologue: bundle0 (A->aR0, B->lds s0), bundle1 (A->aR1, B->lds s1)
  loadA_f32(gA, aR0, tid);
  issueB(gB, ldB, sB, 0, tid);
  loadA_f32(gA + 64, aR1, tid);
  issueB(gB + 64, ldB, sB, 1, tid);
  asm volatile("s_waitcnt vmcnt(6)" ::: "memory");   // bundle0 complete
  writeA(sA, 0, aR0, tid);
  asm volatile("s_waitcnt lgkmcnt(0)" ::: "memory");
  __builtin_amdgcn_s_barrier();
  __builtin_amdgcn_sched_barrier(0);

#pragma unroll
  for (int t = 0; t < 8; ++t) {                      // K=512, BK=64 -> nt=8 (compile-time)
    const unsigned short* sAb = sA + ((t & 1) << 13);
    const unsigned short* sBb = sB + ((t & 1) << 13);
    short8 af[2][4], bfv[4];
    af[0][0] = *(const short8*)(sAb + aoff[0][0]);
    af[1][0] = *(const short8*)(sAb + aoff[1][0]);
    bfv[0]   = *(const short8*)(sBb + boff[0]);
#pragma unroll
    for (int ks = 0; ks < 3; ++ks) {
      af[0][ks + 1] = *(const short8*)(sAb + aoff[0][ks + 1]);
      af[1][ks + 1] = *(const short8*)(sAb + aoff[1][ks + 1]);
      bfv[ks + 1]   = *(const short8*)(sBb + boff[ks + 1]);
      asm volatile("s_waitcnt lgkmcnt(3)" ::: "memory");
      __builtin_amdgcn_sched_barrier(0);
      __builtin_amdgcn_s_setprio(1);
      acc[0] = __builtin_amdgcn_mfma_f32_32x32x16_bf16(af[0][ks], bfv[ks], acc[0], 0, 0, 0);
      acc[1] = __builtin_amdgcn_mfma_f32_32x32x16_bf16(af[1][ks], bfv[ks], acc[1], 0, 0, 0);
      __builtin_amdgcn_s_setprio(0);
    }
    asm volatile("s_waitcnt lgkmcnt(0)" ::: "memory");
    __builtin_amdgcn_sched_barrier(0);
    __builtin_amdgcn_s_barrier();                    // mid: slot t&1 reads done everywhere
    if (t + 2 < 8) {
      if (t & 1) loadA_f32(gA + (size_t)(t + 2) * 64, aR1, tid);
      else       loadA_f32(gA + (size_t)(t + 2) * 64, aR0, tid);
      issueB(gB + (size_t)(t + 2) * 64, ldB, sB, t & 1, tid);
      asm volatile("s_waitcnt vmcnt(6)" ::: "memory");   // bundle t+1 complete
    } else {
      asm volatile("s_waitcnt vmcnt(0)" ::: "memory");
    }
    __builtin_amdgcn_sched_barrier(0);
    if (t + 1 < 8) {                                 // cvt+write A(t+1) -> slot (t+1)&1
      if (t & 1) writeA(sA, (t + 1) & 1, aR0, tid);
      else       writeA(sA, (t + 1) & 1, aR1, tid);
    }
    __builtin_amdgcn_s_setprio(1);
    acc[0] = __builtin_amdgcn_mfma_f32_32x32x16_bf16(af[0][3], bfv[3], acc[0], 0, 0, 0);
    acc[1] = __builtin_amdgcn_mfma_f32_32x32x16_bf16(af[1][3], bfv[3], acc[1], 0, 0, 0);
    __builtin_amdgcn_s_setprio(0);
    asm volatile("s_waitcnt lgkmcnt(0)" ::: "memory");   // drain A ds_writes before barrier
    __builtin_amdgcn_sched_barrier(0);
    __builtin_amdgcn_s_barrier();
    __builtin_amdgcn_sched_barrier(0);
  }
}

// ---------------- GEMM core 64x128 (4 waves) for scores/pv (R17 verbatim) ----------------
__device__ __forceinline__ void issue_tile64(const unsigned short* __restrict__ gA, int ldA,
                                             const unsigned short* __restrict__ gB, int ldB,
                                             unsigned short* sA, unsigned short* sB,
                                             int slot, int tid) {
  unsigned short* dA = sA + (slot << 12);   // 8KB slot
  unsigned short* dB = sB + (slot << 13);   // 16KB slot
#pragma unroll
  for (int c = 0; c < 2; ++c) {
    int li  = (c << 8) + tid;               // 0..511 (A)
    int row = li >> 3;
    int ch  = (li & 7) ^ (row & 7);
    __builtin_amdgcn_global_load_lds((as1_cvp)(gA + (size_t)row * ldA + (ch << 3)),
                                     (as3_vp)(dA + (li << 3)), 16, 0, 0);
  }
#pragma unroll
  for (int c = 0; c < 4; ++c) {
    int li  = (c << 8) + tid;               // 0..1023 (B)
    int row = li >> 3;
    int ch  = (li & 7) ^ (row & 7);
    __builtin_amdgcn_global_load_lds((as1_cvp)(gB + (size_t)row * ldB + (ch << 3)),
                                     (as3_vp)(dB + (li << 3)), 16, 0, 0);
  }
}

// 4 waves (1x4): per-wave 64 rows x 32 cols = acc[2] of 32x32. RSUM: per-thread
// row-sum of the A-tile (2 extra ds_reads AFTER the counted frag reads).
template <bool RSUM>
__device__ __forceinline__ void gemm_pipe64(const unsigned short* __restrict__ gA, int ldA,
                                            const unsigned short* __restrict__ gB, int ldB,
                                            int nt, unsigned short* sA, unsigned short* sB,
                                            int tid, f32x16 acc[2], float* lacc) {
  const int l = tid & 63, w = tid >> 6;
  const int cl = l & 31, hi = l >> 5;
  int aoff[2][4], boff[4];
#pragma unroll
  for (int m = 0; m < 2; ++m) {
    int ra = m * 32 + cl;
#pragma unroll
    for (int ks = 0; ks < 4; ++ks) {
      int kc = ks * 2 + hi;
      aoff[m][ks] = ra * 64 + ((kc ^ (ra & 7)) << 3);
    }
  }
  {
    int rb = w * 32 + cl;
#pragma unroll
    for (int ks = 0; ks < 4; ++ks) {
      int kc = ks * 2 + hi;
      boff[ks] = rb * 64 + ((kc ^ (rb & 7)) << 3);
    }
  }
  const int srow = tid >> 2;
  const int kc0  = (tid & 3) * 2;
  const int soff0 = srow * 64 + (((kc0)     ^ (srow & 7)) << 3);
  const int soff1 = srow * 64 + (((kc0 + 1) ^ (srow & 7)) << 3);

  issue_tile64(gA, ldA, gB, ldB, sA, sB, 0, tid);
  issue_tile64(gA + 64, ldA, gB + 64, ldB, sA, sB, 1, tid);
  asm volatile("s_waitcnt vmcnt(6)" ::: "memory");
  __builtin_amdgcn_s_barrier();
  __builtin_amdgcn_sched_barrier(0);

  for (int t = 0; t < nt; ++t) {
    const unsigned short* sAb = sA + ((t & 1) << 12);
    const unsigned short* sBb = sB + ((t & 1) << 13);
    short8 af[2][4], bfv[4], sr0, sr1;
    af[0][0] = *(const short8*)(sAb + aoff[0][0]);
    af[1][0] = *(const short8*)(sAb + aoff[1][0]);
    bfv[0]   = *(const short8*)(sBb + boff[0]);
#pragma unroll
    for (int ks = 0; ks < 3; ++ks) {
      af[0][ks + 1] = *(const short8*)(sAb + aoff[0][ks + 1]);
      af[1][ks + 1] = *(const short8*)(sAb + aoff[1][ks + 1]);
      bfv[ks + 1]   = *(const short8*)(sBb + boff[ks + 1]);
      asm volatile("s_waitcnt lgkmcnt(3)" ::: "memory");
      __builtin_amdgcn_sched_barrier(0);
      __builtin_amdgcn_s_setprio(1);
      acc[0] = __builtin_amdgcn_mfma_f32_32x32x16_bf16(af[0][ks], bfv[ks], acc[0], 0, 0, 0);
      acc[1] = __builtin_amdgcn_mfma_f32_32x32x16_bf16(af[1][ks], bfv[ks], acc[1], 0, 0, 0);
      __builtin_amdgcn_s_setprio(0);
    }
    if (RSUM) {
      sr0 = *(const short8*)(sAb + soff0);
      sr1 = *(const short8*)(sAb + soff1);
    }
    asm volatile("s_waitcnt lgkmcnt(0)" ::: "memory");
    __builtin_amdgcn_sched_barrier(0);
    __builtin_amdgcn_s_barrier();
    if (t + 2 < nt) {
      issue_tile64(gA + (size_t)(t + 2) * 64, ldA, gB + (size_t)(t + 2) * 64, ldB, sA, sB, t & 1, tid);
      asm volatile("s_waitcnt vmcnt(6)" ::: "memory");
    } else {
      asm volatile("s_waitcnt vmcnt(0)" ::: "memory");
    }
    __builtin_amdgcn_sched_barrier(0);
    if (RSUM) {
      float ls = 0.0f;
#pragma unroll
      for (int j = 0; j < 8; ++j) ls += bf2f((unsigned short)sr0[j]) + bf2f((unsigned short)sr1[j]);
      *lacc += ls;
    }
    __builtin_amdgcn_s_setprio(1);
    acc[0] = __builtin_amdgcn_mfma_f32_32x32x16_bf16(af[0][3], bfv[3], acc[0], 0, 0, 0);
    acc[1] = __builtin_amdgcn_mfma_f32_32x32x16_bf16(af[1][3], bfv[3], acc[1], 0, 0, 0);
    __builtin_amdgcn_s_setprio(0);
    __builtin_amdgcn_s_barrier();
    __builtin_amdgcn_sched_barrier(0);
  }
}

// C/D mapping 32x32 (m74/m101): col = lane&31, row = (reg&3) + 8*(reg>>2) + 4*(lane>>5).

// ---------------- K2: QKV + bias + RoPE, V transposed — A direct from FP32 x ----------
__global__ __launch_bounds__(512, 4) void qkv_kernel(const float* __restrict__ x,
                                                     const unsigned short* __restrict__ wb,
                                                     const float* __restrict__ bq,
                                                     const float* __restrict__ bk,
                                                     const float* __restrict__ bv,
                                                     const float2* __restrict__ tab,
                                                     unsigned short* __restrict__ qrot,
                                                     unsigned short* __restrict__ krot,
                                                     unsigned short* __restrict__ vt) {
  __shared__ __align__(16) unsigned short sA[2 * 8192];
  __shared__ __align__(16) unsigned short sB[2 * 8192];
  int id = blockIdx.x;
  int b3 = id & 7, rest = id >> 3;          // rest in [0,96)
  int ntile = rest % 12, mhi = rest / 12;   // mhi in [0,8)
  int m0 = (mhi * 8 + b3) * 128, n0 = ntile * 128;
  int t = threadIdx.x, w = t >> 6, l = t & 63, wr = w >> 2, wc = w & 3;
  int cl = l & 31, hi = l >> 5;
  f32x16 acc[2] = {};
  gemm_pipe_xf32(x + (size_t)m0 * 512, wb + (size_t)n0 * 512, 512, sA, sB, t, acc);

  int sec = n0 >> 9;
  const float* bias = (sec == 0) ? bq : (sec == 1) ? bk : bv;
  unsigned short* qk_dst = (sec == 0) ? qrot : krot;
  int e = (n0 + wc * 32 + cl) & 511;
  float bsv = bias[e];
  if (sec < 2) {
    int i2 = e >> 1;
#pragma unroll
    for (int m = 0; m < 2; ++m) {
      int rowb = m0 + wr * 64 + m * 32 + 4 * hi;
#pragma unroll
      for (int r = 0; r < 16; ++r) {
        int mg = rowb + (r & 3) + 8 * (r >> 2);
        int cpos = mg & (CTXN - 1);
        float val  = acc[m][r] + bsv;
        float part = __shfl_xor(val, 1);
        float2 cs  = tab[cpos * 256 + i2];
        float o = (e & 1) ? fmaf(part, cs.y, val * cs.x)
                          : fmaf(-part, cs.y, val * cs.x);
        qk_dst[(size_t)mg * 512 + e] = f2bf(o);
      }
    }
  } else {
#pragma unroll
    for (int m = 0; m < 2; ++m) {
      int rowb0 = m0 + wr * 64 + m * 32 + 4 * hi;
#pragma unroll
      for (int q = 0; q < 4; ++q) {
        int rowb = rowb0 + 8 * q;
        int bidx = rowb >> 10;
        int cpos = rowb & (CTXN - 1);
        ushort4 pk;
        pk.x = f2bf(acc[m][q * 4 + 0] + bsv);
        pk.y = f2bf(acc[m][q * 4 + 1] + bsv);
        pk.z = f2bf(acc[m][q * 4 + 2] + bsv);
        pk.w = f2bf(acc[m][q * 4 + 3] + bsv);
        *(ushort4*)(vt + ((size_t)bidx * 512 + e) * 1024 + cpos) = pk;  // vt[b][d][c]
      }
    }
  }
}

// ---------------- K3: scores -> P_unnorm = exp(s*scale), XCD-affine (R17 verbatim) -------
__device__ const unsigned char T64_IT[72] = {
  0,1,2,2,3,3,4,4,4,5,5,5,6,6,6,6,7,7,7,7,
  8,8,8,8,8,9,9,9,9,9,10,10,10,10,10,10,11,11,11,11,11,11,
  12,12,12,12,12,12,12,13,13,13,13,13,13,13,
  14,14,14,14,14,14,14,14,15,15,15,15,15,15,15,15};
__device__ const unsigned char T64_JT[72] = {
  0,0,0,1,0,1,0,1,2,0,1,2,0,1,2,3,0,1,2,3,
  0,1,2,3,4,0,1,2,3,4,0,1,2,3,4,5,0,1,2,3,4,5,
  0,1,2,3,4,5,6,0,1,2,3,4,5,6,
  0,1,2,3,4,5,6,7,0,1,2,3,4,5,6,7};

__global__ __launch_bounds__(256, 3) void scores_kernel(const unsigned short* __restrict__ qr,
                                                        const unsigned short* __restrict__ kr,
                                                        unsigned short* __restrict__ P) {
  int id = blockIdx.x;                // 576 = 72*8; id&7 = batch -> XCD-resident K
  int b = id & 7, tri = id >> 3;
  int it = T64_IT[tri], jt = T64_JT[tri];
  __shared__ __align__(16) unsigned short sA[2 * 4096];
  __shared__ __align__(16) unsigned short sB[2 * 8192];
  int t = threadIdx.x, w = t >> 6, l = t & 63;
  int cl = l & 31, hi = l >> 5;
  const unsigned short* A  = qr + ((size_t)b << 19) + (size_t)it * 64 * 512;
  const unsigned short* Bp = kr + ((size_t)b << 19) + (size_t)jt * 128 * 512;
  f32x16 acc[2] = {};
  float dummy = 0.0f;
  gemm_pipe64<false>(A, 512, Bp, 512, 8, sA, sB, t, acc, &dummy);

  const float scale = 0.04419417382415922f;  // 1/sqrt(512)
  unsigned short* Pb = P + ((size_t)b << 20);
  int j = jt * 128 + w * 32 + cl;
#pragma unroll
  for (int m = 0; m < 2; ++m) {
    int iqb = it * 64 + m * 32 + 4 * hi;
#pragma unroll
    for (int r = 0; r < 16; ++r) {
      int row = iqb + (r & 3) + 8 * (r >> 2);
      float p = (j <= row) ? __expf(acc[m][r] * scale) : 0.0f;
      Pb[(size_t)row * 1024 + j] = f2bf(p);
    }
  }
}

// ---------------- K4: out = (P@V)/rowsum — paired its, XCD-affine (R17 verbatim) ---------
__global__ __launch_bounds__(256, 3) void pv_kernel(const unsigned short* __restrict__ P,
                                                    const unsigned short* __restrict__ vt,
                                                    float* __restrict__ out) {
  int id = blockIdx.x;                // 256 = 8 pairs * 4 d-tiles * 8 batch; id&7 = batch
  int b = id & 7, rest = id >> 3;     // rest in [0,32)
  int pr = rest & 7, nt2 = rest >> 3; // pair index, d-tile
  __shared__ __align__(16) unsigned short sA[2 * 4096];
  __shared__ __align__(16) unsigned short sB[2 * 8192];
  __shared__ float lpart[64][4];
  __shared__ float lsum[64];
  int t = threadIdx.x, w = t >> 6, l = t & 63;
  int cl = l & 31, hi = l >> 5;
  const unsigned short* Bp = vt + ((size_t)b << 19) + (size_t)nt2 * 128 * 1024;
  float* ob = out + ((size_t)b << 19);
  int d = nt2 * 128 + w * 32 + cl;

#pragma unroll
  for (int h = 0; h < 2; ++h) {
    int it = h ? (15 - pr) : pr;
    const unsigned short* A = P + ((size_t)b << 20) + (size_t)it * 64 * 1024;
    int nt = ((it >> 1) + 1) * 2;     // causal K-tiles; nt(it)+nt(15-it) = 18 uniform
    f32x16 acc[2] = {};
    float lacc = 0.0f;
    gemm_pipe64<true>(A, 1024, Bp, 1024, nt, sA, sB, t, acc, &lacc);

    lpart[t >> 2][t & 3] = lacc;
    __syncthreads();
    if (t < 64) lsum[t] = (lpart[t][0] + lpart[t][1]) + (lpart[t][2] + lpart[t][3]);
    __syncthreads();

#pragma unroll
    for (int m = 0; m < 2; ++m) {
      int rl0 = m * 32 + 4 * hi;
#pragma unroll
      for (int r = 0; r < 16; ++r) {
        int rl = rl0 + (r & 3) + 8 * (r >> 2);
        ob[(size_t)(it * 64 + rl) * 512 + d] = acc[m][r] * (1.0f / lsum[rl]);
      }
    }
    __syncthreads();                  // lsum/lpart reuse guard before next half
  }
}

// ---------------- launch ----------------
extern "C" void kernel_launch(void* const* d_in, const int* in_sizes, int n_in,
                              void* d_out, int out_size, void* d_ws, size_t ws_size,
                              hipStream_t stream) {
  const float* x  = (const float*)d_in[0];
  const float* wq = (const float*)d_in[1];
  const float* bq = (const float*)d_in[2];
  const float* wk = (const float*)d_in[3];
  const float* bk = (const float*)d_in[4];
  const float* wv = (const float*)d_in[5];
  const float* bv = (const float*)d_in[6];
  float* out = (float*)d_out;

  char* ws = (char*)d_ws;
  float2*         tab  = (float2*)(ws);                          //  2 MB
  unsigned short* wb   = (unsigned short*)(ws + (10ull << 20));  //  1.5 MB
  unsigned short* qrot = (unsigned short*)(ws + (12ull << 20));  //  8 MB
  unsigned short* krot = (unsigned short*)(ws + (20ull << 20));  //  8 MB
  unsigned short* vt   = (unsigned short*)(ws + (28ull << 20));  //  8 MB
  unsigned short* P    = (unsigned short*)(ws + (36ull << 20));  // 16 MB (P_unnorm bf16)

  prep_all<<<dim3(WCAST_BLOCKS + CTXN), dim3(256), 0, stream>>>(wq, wk, wv, wb, tab);
  qkv_kernel<<<dim3(768), dim3(512), 0, stream>>>(x, wb, bq, bk, bv, tab, qrot, krot, vt);
  scores_kernel<<<dim3(576), dim3(256), 0, stream>>>(qrot, krot, P);
  pv_kernel<<<dim3(256), dim3(256), 0, stream>>>(P, vt, out);
}

// Round 20
// 65.360 us; speedup vs baseline: 1.0922x; 1.0922x over previous
//
#include <hip/hip_runtime.h>

// Problem: B=8, CTX=1024, D=512 RoPE attention head, fp32 in/out, bf16-tolerance.
#define BATCH 8
#define CTXN  1024
#define DMODEL 512

using short8  = __attribute__((ext_vector_type(8))) short;
using f32x16  = __attribute__((ext_vector_type(16))) float;

typedef const void __attribute__((address_space(1)))* as1_cvp;
typedef void __attribute__((address_space(3)))* as3_vp;

__device__ __forceinline__ unsigned short f2bf(float f) {
  unsigned int u = __float_as_uint(f);
  u += 0x7fffu + ((u >> 16) & 1u);   // round-to-nearest-even
  return (unsigned short)(u >> 16);
}
__device__ __forceinline__ float bf2f(unsigned short u) {
  return __uint_as_float((unsigned int)u << 16);
}

// ---------------- fused prep: bf16 casts + RoPE cos/sin table, one launch ----------------
#define X4  1048576   // 8*1024*512/4
#define W4  65536     // 512*512/4
#define CAST_BLOCKS 4864   // (X4+3*W4)/256
__global__ __launch_bounds__(256) void prep_all(const float* __restrict__ x,
                                                const float* __restrict__ wq,
                                                const float* __restrict__ wk,
                                                const float* __restrict__ wv,
                                                unsigned short* __restrict__ xb,
                                                unsigned short* __restrict__ wb,
                                                float2* __restrict__ tab) {
  if (blockIdx.x < CAST_BLOCKS) {
    int gid = blockIdx.x * 256 + threadIdx.x;
    const float4* src; ushort4* dst;
    if (gid < X4)                { src = (const float4*)x  + gid;              dst = (ushort4*)xb + gid; }
    else if (gid < X4 + W4)      { int o = gid - X4;        src = (const float4*)wq + o; dst = (ushort4*)wb + o; }
    else if (gid < X4 + 2 * W4)  { int o = gid - X4 - W4;   src = (const float4*)wk + o; dst = (ushort4*)(wb + 262144) + o; }
    else                         { int o = gid - X4 - 2*W4; src = (const float4*)wv + o; dst = (ushort4*)(wb + 524288) + o; }
    float4 f = *src;
    ushort4 u;
    u.x = f2bf(f.x); u.y = f2bf(f.y); u.z = f2bf(f.z); u.w = f2bf(f.w);
    *dst = u;
  } else {
    int c = blockIdx.x - CAST_BLOCKS;   // 0..1023
    int i = threadIdx.x;                // 0..255 = D/2
    float freq = exp2f((float)i * (-13.287712379549449f / 256.0f));  // 10000^(-i/256)
    float th = (float)c * freq;
    float sn, cs;
    sincosf(th, &sn, &cs);
    tab[c * 256 + i] = make_float2(cs, sn);
  }
}

// ---------------- GEMM core 128x128 (8 waves) for QKV — R6/R10 proven ----------------
__device__ __forceinline__ void issue_tile(const unsigned short* __restrict__ gA, int ldA,
                                           const unsigned short* __restrict__ gB, int ldB,
                                           unsigned short* sA, unsigned short* sB,
                                           int slot, int tid) {
  unsigned short* dA = sA + (slot << 13);
  unsigned short* dB = sB + (slot << 13);
#pragma unroll
  for (int c = 0; c < 2; ++c) {
    int li  = (c << 9) + tid;
    int row = li >> 3;
    int ch  = (li & 7) ^ (row & 7);
    __builtin_amdgcn_global_load_lds((as1_cvp)(gA + (size_t)row * ldA + (ch << 3)),
                                     (as3_vp)(dA + (li << 3)), 16, 0, 0);
  }
#pragma unroll
  for (int c = 0; c < 2; ++c) {
    int li  = (c << 9) + tid;
    int row = li >> 3;
    int ch  = (li & 7) ^ (row & 7);
    __builtin_amdgcn_global_load_lds((as1_cvp)(gB + (size_t)row * ldB + (ch << 3)),
                                     (as3_vp)(dB + (li << 3)), 16, 0, 0);
  }
}

__device__ __forceinline__ void gemm_pipe(const unsigned short* __restrict__ gA, int ldA,
                                          const unsigned short* __restrict__ gB, int ldB,
                                          int nt, unsigned short* sA, unsigned short* sB,
                                          int tid, f32x16 acc[2]) {
  const int l = tid & 63, w = tid >> 6, wr = w >> 2, wc = w & 3;
  const int cl = l & 31, hi = l >> 5;
  int aoff[2][4], boff[4];
#pragma unroll
  for (int m = 0; m < 2; ++m) {
    int ra = wr * 64 + m * 32 + cl;
#pragma unroll
    for (int ks = 0; ks < 4; ++ks) {
      int kc = ks * 2 + hi;
      aoff[m][ks] = ra * 64 + ((kc ^ (ra & 7)) << 3);
    }
  }
  {
    int rb = wc * 32 + cl;
#pragma unroll
    for (int ks = 0; ks < 4; ++ks) {
      int kc = ks * 2 + hi;
      boff[ks] = rb * 64 + ((kc ^ (rb & 7)) << 3);
    }
  }
  issue_tile(gA, ldA, gB, ldB, sA, sB, 0, tid);
  issue_tile(gA + 64, ldA, gB + 64, ldB, sA, sB, 1, tid);
  asm volatile("s_waitcnt vmcnt(4)" ::: "memory");
  __builtin_amdgcn_s_barrier();
  __builtin_amdgcn_sched_barrier(0);

  for (int t = 0; t < nt; ++t) {
    const unsigned short* sAb = sA + ((t & 1) << 13);
    const unsigned short* sBb = sB + ((t & 1) << 13);
    short8 af[2][4], bfv[4];
    af[0][0] = *(const short8*)(sAb + aoff[0][0]);
    af[1][0] = *(const short8*)(sAb + aoff[1][0]);
    bfv[0]   = *(const short8*)(sBb + boff[0]);
#pragma unroll
    for (int ks = 0; ks < 3; ++ks) {
      af[0][ks + 1] = *(const short8*)(sAb + aoff[0][ks + 1]);
      af[1][ks + 1] = *(const short8*)(sAb + aoff[1][ks + 1]);
      bfv[ks + 1]   = *(const short8*)(sBb + boff[ks + 1]);
      asm volatile("s_waitcnt lgkmcnt(3)" ::: "memory");
      __builtin_amdgcn_sched_barrier(0);
      __builtin_amdgcn_s_setprio(1);
      acc[0] = __builtin_amdgcn_mfma_f32_32x32x16_bf16(af[0][ks], bfv[ks], acc[0], 0, 0, 0);
      acc[1] = __builtin_amdgcn_mfma_f32_32x32x16_bf16(af[1][ks], bfv[ks], acc[1], 0, 0, 0);
      __builtin_amdgcn_s_setprio(0);
    }
    asm volatile("s_waitcnt lgkmcnt(0)" ::: "memory");
    __builtin_amdgcn_sched_barrier(0);
    __builtin_amdgcn_s_barrier();
    if (t + 2 < nt) {
      issue_tile(gA + (size_t)(t + 2) * 64, ldA, gB + (size_t)(t + 2) * 64, ldB, sA, sB, t & 1, tid);
      asm volatile("s_waitcnt vmcnt(4)" ::: "memory");
    } else {
      asm volatile("s_waitcnt vmcnt(0)" ::: "memory");
    }
    __builtin_amdgcn_sched_barrier(0);
    __builtin_amdgcn_s_setprio(1);
    acc[0] = __builtin_amdgcn_mfma_f32_32x32x16_bf16(af[0][3], bfv[3], acc[0], 0, 0, 0);
    acc[1] = __builtin_amdgcn_mfma_f32_32x32x16_bf16(af[1][3], bfv[3], acc[1], 0, 0, 0);
    __builtin_amdgcn_s_setprio(0);
    __builtin_amdgcn_s_barrier();
    __builtin_amdgcn_sched_barrier(0);
  }
}

// ---------------- GEMM core 64x128 (4 waves) for scores/pv ----------------
__device__ __forceinline__ void issue_tile64(const unsigned short* __restrict__ gA, int ldA,
                                             const unsigned short* __restrict__ gB, int ldB,
                                             unsigned short* sA, unsigned short* sB,
                                             int slot, int tid) {
  unsigned short* dA = sA + (slot << 12);   // 8KB slot
  unsigned short* dB = sB + (slot << 13);   // 16KB slot
#pragma unroll
  for (int c = 0; c < 2; ++c) {
    int li  = (c << 8) + tid;               // 0..511 (A)
    int row = li >> 3;
    int ch  = (li & 7) ^ (row & 7);
    __builtin_amdgcn_global_load_lds((as1_cvp)(gA + (size_t)row * ldA + (ch << 3)),
                                     (as3_vp)(dA + (li << 3)), 16, 0, 0);
  }
#pragma unroll
  for (int c = 0; c < 4; ++c) {
    int li  = (c << 8) + tid;               // 0..1023 (B)
    int row = li >> 3;
    int ch  = (li & 7) ^ (row & 7);
    __builtin_amdgcn_global_load_lds((as1_cvp)(gB + (size_t)row * ldB + (ch << 3)),
                                     (as3_vp)(dB + (li << 3)), 16, 0, 0);
  }
}

// 4 waves (1x4): per-wave 64 rows x 32 cols = acc[2] of 32x32. RSUM: per-thread
// row-sum of the A-tile (2 extra ds_reads AFTER the counted frag reads).
template <bool RSUM>
__device__ __forceinline__ void gemm_pipe64(const unsigned short* __restrict__ gA, int ldA,
                                            const unsigned short* __restrict__ gB, int ldB,
                                            int nt, unsigned short* sA, unsigned short* sB,
                                            int tid, f32x16 acc[2], float* lacc) {
  const int l = tid & 63, w = tid >> 6;
  const int cl = l & 31, hi = l >> 5;
  int aoff[2][4], boff[4];
#pragma unroll
  for (int m = 0; m < 2; ++m) {
    int ra = m * 32 + cl;
#pragma unroll
    for (int ks = 0; ks < 4; ++ks) {
      int kc = ks * 2 + hi;
      aoff[m][ks] = ra * 64 + ((kc ^ (ra & 7)) << 3);
    }
  }
  {
    int rb = w * 32 + cl;
#pragma unroll
    for (int ks = 0; ks < 4; ++ks) {
      int kc = ks * 2 + hi;
      boff[ks] = rb * 64 + ((kc ^ (rb & 7)) << 3);
    }
  }
  const int srow = tid >> 2;
  const int kc0  = (tid & 3) * 2;
  const int soff0 = srow * 64 + (((kc0)     ^ (srow & 7)) << 3);
  const int soff1 = srow * 64 + (((kc0 + 1) ^ (srow & 7)) << 3);

  issue_tile64(gA, ldA, gB, ldB, sA, sB, 0, tid);
  issue_tile64(gA + 64, ldA, gB + 64, ldB, sA, sB, 1, tid);
  asm volatile("s_waitcnt vmcnt(6)" ::: "memory");
  __builtin_amdgcn_s_barrier();
  __builtin_amdgcn_sched_barrier(0);

  for (int t = 0; t < nt; ++t) {
    const unsigned short* sAb = sA + ((t & 1) << 12);
    const unsigned short* sBb = sB + ((t & 1) << 13);
    short8 af[2][4], bfv[4], sr0, sr1;
    af[0][0] = *(const short8*)(sAb + aoff[0][0]);
    af[1][0] = *(const short8*)(sAb + aoff[1][0]);
    bfv[0]   = *(const short8*)(sBb + boff[0]);
#pragma unroll
    for (int ks = 0; ks < 3; ++ks) {
      af[0][ks + 1] = *(const short8*)(sAb + aoff[0][ks + 1]);
      af[1][ks + 1] = *(const short8*)(sAb + aoff[1][ks + 1]);
      bfv[ks + 1]   = *(const short8*)(sBb + boff[ks + 1]);
      asm volatile("s_waitcnt lgkmcnt(3)" ::: "memory");
      __builtin_amdgcn_sched_barrier(0);
      __builtin_amdgcn_s_setprio(1);
      acc[0] = __builtin_amdgcn_mfma_f32_32x32x16_bf16(af[0][ks], bfv[ks], acc[0], 0, 0, 0);
      acc[1] = __builtin_amdgcn_mfma_f32_32x32x16_bf16(af[1][ks], bfv[ks], acc[1], 0, 0, 0);
      __builtin_amdgcn_s_setprio(0);
    }
    if (RSUM) {
      sr0 = *(const short8*)(sAb + soff0);
      sr1 = *(const short8*)(sAb + soff1);
    }
    asm volatile("s_waitcnt lgkmcnt(0)" ::: "memory");
    __builtin_amdgcn_sched_barrier(0);
    __builtin_amdgcn_s_barrier();
    if (t + 2 < nt) {
      issue_tile64(gA + (size_t)(t + 2) * 64, ldA, gB + (size_t)(t + 2) * 64, ldB, sA, sB, t & 1, tid);
      asm volatile("s_waitcnt vmcnt(6)" ::: "memory");
    } else {
      asm volatile("s_waitcnt vmcnt(0)" ::: "memory");
    }
    __builtin_amdgcn_sched_barrier(0);
    if (RSUM) {
      float ls = 0.0f;
#pragma unroll
      for (int j = 0; j < 8; ++j) ls += bf2f((unsigned short)sr0[j]) + bf2f((unsigned short)sr1[j]);
      *lacc += ls;
    }
    __builtin_amdgcn_s_setprio(1);
    acc[0] = __builtin_amdgcn_mfma_f32_32x32x16_bf16(af[0][3], bfv[3], acc[0], 0, 0, 0);
    acc[1] = __builtin_amdgcn_mfma_f32_32x32x16_bf16(af[1][3], bfv[3], acc[1], 0, 0, 0);
    __builtin_amdgcn_s_setprio(0);
    __builtin_amdgcn_s_barrier();
    __builtin_amdgcn_sched_barrier(0);
  }
}

// C/D mapping 32x32 (m74/m101): col = lane&31, row = (reg&3) + 8*(reg>>2) + 4*(lane>>5).

// ---------------- K2: QKV + bias + RoPE, V transposed — XCD-affine 1-D grid ----------
__global__ __launch_bounds__(512, 4) void qkv_kernel(const unsigned short* __restrict__ xb,
                                                     const unsigned short* __restrict__ wb,
                                                     const float* __restrict__ bq,
                                                     const float* __restrict__ bk,
                                                     const float* __restrict__ bv,
                                                     const float2* __restrict__ tab,
                                                     unsigned short* __restrict__ qrot,
                                                     unsigned short* __restrict__ krot,
                                                     unsigned short* __restrict__ vt) {
  __shared__ __align__(16) unsigned short sA[2 * 8192];
  __shared__ __align__(16) unsigned short sB[2 * 8192];
  int id = blockIdx.x;
  int b3 = id & 7, rest = id >> 3;          // rest in [0,96)
  int ntile = rest % 12, mhi = rest / 12;   // mhi in [0,8)
  int m0 = (mhi * 8 + b3) * 128, n0 = ntile * 128;
  int t = threadIdx.x, w = t >> 6, l = t & 63, wr = w >> 2, wc = w & 3;
  int cl = l & 31, hi = l >> 5;
  f32x16 acc[2] = {};
  gemm_pipe(xb + (size_t)m0 * 512, 512, wb + (size_t)n0 * 512, 512, 8, sA, sB, t, acc);

  int sec = n0 >> 9;
  const float* bias = (sec == 0) ? bq : (sec == 1) ? bk : bv;
  unsigned short* qk_dst = (sec == 0) ? qrot : krot;
  int e = (n0 + wc * 32 + cl) & 511;
  float bsv = bias[e];
  if (sec < 2) {
    int i2 = e >> 1;
#pragma unroll
    for (int m = 0; m < 2; ++m) {
      int rowb = m0 + wr * 64 + m * 32 + 4 * hi;
#pragma unroll
      for (int r = 0; r < 16; ++r) {
        int mg = rowb + (r & 3) + 8 * (r >> 2);
        int cpos = mg & (CTXN - 1);
        float val  = acc[m][r] + bsv;
        float part = __shfl_xor(val, 1);
        float2 cs  = tab[cpos * 256 + i2];
        float o = (e & 1) ? fmaf(part, cs.y, val * cs.x)
                          : fmaf(-part, cs.y, val * cs.x);
        qk_dst[(size_t)mg * 512 + e] = f2bf(o);
      }
    }
  } else {
#pragma unroll
    for (int m = 0; m < 2; ++m) {
      int rowb0 = m0 + wr * 64 + m * 32 + 4 * hi;
#pragma unroll
      for (int q = 0; q < 4; ++q) {
        int rowb = rowb0 + 8 * q;
        int bidx = rowb >> 10;
        int cpos = rowb & (CTXN - 1);
        ushort4 pk;
        pk.x = f2bf(acc[m][q * 4 + 0] + bsv);
        pk.y = f2bf(acc[m][q * 4 + 1] + bsv);
        pk.z = f2bf(acc[m][q * 4 + 2] + bsv);
        pk.w = f2bf(acc[m][q * 4 + 3] + bsv);
        *(ushort4*)(vt + ((size_t)bidx * 512 + e) * 1024 + cpos) = pk;  // vt[b][d][c]
      }
    }
  }
}

// ---------------- K3: scores -> P_unnorm = exp(s*scale), XCD-affine (id&7 = batch) -------
__device__ const unsigned char T64_IT[72] = {
  0,1,2,2,3,3,4,4,4,5,5,5,6,6,6,6,7,7,7,7,
  8,8,8,8,8,9,9,9,9,9,10,10,10,10,10,10,11,11,11,11,11,11,
  12,12,12,12,12,12,12,13,13,13,13,13,13,13,
  14,14,14,14,14,14,14,14,15,15,15,15,15,15,15,15};
__device__ const unsigned char T64_JT[72] = {
  0,0,0,1,0,1,0,1,2,0,1,2,0,1,2,3,0,1,2,3,
  0,1,2,3,4,0,1,2,3,4,0,1,2,3,4,5,0,1,2,3,4,5,
  0,1,2,3,4,5,6,0,1,2,3,4,5,6,
  0,1,2,3,4,5,6,7,0,1,2,3,4,5,6,7};

__global__ __launch_bounds__(256, 3) void scores_kernel(const unsigned short* __restrict__ qr,
                                                        const unsigned short* __restrict__ kr,
                                                        unsigned short* __restrict__ P) {
  int id = blockIdx.x;                // 576 = 72*8; id&7 = batch -> XCD-resident K
  int b = id & 7, tri = id >> 3;
  int it = T64_IT[tri], jt = T64_JT[tri];
  __shared__ __align__(16) unsigned short sA[2 * 4096];
  __shared__ __align__(16) unsigned short sB[2 * 8192];
  int t = threadIdx.x, w = t >> 6, l = t & 63;
  int cl = l & 31, hi = l >> 5;
  const unsigned short* A  = qr + ((size_t)b << 19) + (size_t)it * 64 * 512;
  const unsigned short* Bp = kr + ((size_t)b << 19) + (size_t)jt * 128 * 512;
  f32x16 acc[2] = {};
  float dummy = 0.0f;
  gemm_pipe64<false>(A, 512, Bp, 512, 8, sA, sB, t, acc, &dummy);

  const float scale = 0.04419417382415922f;  // 1/sqrt(512)
  unsigned short* Pb = P + ((size_t)b << 20);
  int j = jt * 128 + w * 32 + cl;
#pragma unroll
  for (int m = 0; m < 2; ++m) {
    int iqb = it * 64 + m * 32 + 4 * hi;
#pragma unroll
    for (int r = 0; r < 16; ++r) {
      int row = iqb + (r & 3) + 8 * (r >> 2);
      float p = (j <= row) ? __expf(acc[m][r] * scale) : 0.0f;
      Pb[(size_t)row * 1024 + j] = f2bf(p);
    }
  }
}

// ---------------- K4: out = (P@V)/rowsum — it paired with 15-it (uniform 18 K-tiles) -----
__global__ __launch_bounds__(256, 3) void pv_kernel(const unsigned short* __restrict__ P,
                                                    const unsigned short* __restrict__ vt,
                                                    float* __restrict__ out) {
  int id = blockIdx.x;                // 256 = 8 pairs * 4 d-tiles * 8 batch; id&7 = batch
  int b = id & 7, rest = id >> 3;     // rest in [0,32)
  int pr = rest & 7, nt2 = rest >> 3; // pair index, d-tile
  __shared__ __align__(16) unsigned short sA[2 * 4096];
  __shared__ __align__(16) unsigned short sB[2 * 8192];
  __shared__ float lpart[64][4];
  __shared__ float lsum[64];
  int t = threadIdx.x, w = t >> 6, l = t & 63;
  int cl = l & 31, hi = l >> 5;
  const unsigned short* Bp = vt + ((size_t)b << 19) + (size_t)nt2 * 128 * 1024;
  float* ob = out + ((size_t)b << 19);
  int d = nt2 * 128 + w * 32 + cl;

#pragma unroll
  for (int h = 0; h < 2; ++h) {
    int it = h ? (15 - pr) : pr;
    const unsigned short* A = P + ((size_t)b << 20) + (size_t)it * 64 * 1024;
    int nt = ((it >> 1) + 1) * 2;     // causal K-tiles; nt(it)+nt(15-it) = 18 uniform
    f32x16 acc[2] = {};
    float lacc = 0.0f;
    gemm_pipe64<true>(A, 1024, Bp, 1024, nt, sA, sB, t, acc, &lacc);

    lpart[t >> 2][t & 3] = lacc;
    __syncthreads();
    if (t < 64) lsum[t] = (lpart[t][0] + lpart[t][1]) + (lpart[t][2] + lpart[t][3]);
    __syncthreads();

#pragma unroll
    for (int m = 0; m < 2; ++m) {
      int rl0 = m * 32 + 4 * hi;
#pragma unroll
      for (int r = 0; r < 16; ++r) {
        int rl = rl0 + (r & 3) + 8 * (r >> 2);
        ob[(size_t)(it * 64 + rl) * 512 + d] = acc[m][r] * (1.0f / lsum[rl]);
      }
    }
    __syncthreads();                  // lsum/lpart reuse guard before next half
  }
}

// ---------------- launch ----------------
extern "C" void kernel_launch(void* const* d_in, const int* in_sizes, int n_in,
                              void* d_out, int out_size, void* d_ws, size_t ws_size,
                              hipStream_t stream) {
  const float* x  = (const float*)d_in[0];
  const float* wq = (const float*)d_in[1];
  const float* bq = (const float*)d_in[2];
  const float* wk = (const float*)d_in[3];
  const float* bk = (const float*)d_in[4];
  const float* wv = (const float*)d_in[5];
  const float* bv = (const float*)d_in[6];
  float* out = (float*)d_out;

  char* ws = (char*)d_ws;
  float2*         tab  = (float2*)(ws);                          //  2 MB
  unsigned short* xb   = (unsigned short*)(ws + (2ull  << 20));  //  8 MB
  unsigned short* wb   = (unsigned short*)(ws + (10ull << 20));  //  1.5 MB
  unsigned short* qrot = (unsigned short*)(ws + (12ull << 20));  //  8 MB
  unsigned short* krot = (unsigned short*)(ws + (20ull << 20));  //  8 MB
  unsigned short* vt   = (unsigned short*)(ws + (28ull << 20));  //  8 MB
  unsigned short* P    = (unsigned short*)(ws + (36ull << 20));  // 16 MB (P_unnorm bf16)

  prep_all<<<dim3(CAST_BLOCKS + CTXN), dim3(256), 0, stream>>>(x, wq, wk, wv, xb, wb, tab);
  qkv_kernel<<<dim3(768), dim3(512), 0, stream>>>(xb, wb, bq, bk, bv, tab, qrot, krot, vt);
  scores_kernel<<<dim3(576), dim3(256), 0, stream>>>(qrot, krot, P);
  pv_kernel<<<dim3(256), dim3(256), 0, stream>>>(P, vt, out);
}